// Round 1
// 185.180 us; speedup vs baseline: 1.0173x; 1.0173x over previous
//
#include <hip/hip_runtime.h>
#include <hip/hip_bf16.h>
#include <cstdint>

// MultiHeadSelfAttention N=2,L=2048,E=1024,H=16,D=64.
// Round 5: attn rewritten on mfma_f32_32x32x16_bf16: 32q/wave, 128q/block,
// grid 512 XCD-grouped (all q-blocks of a head share one L2). Swapped QK^T
// keeps P lane-local -> in-register softmax (cvt_pk + permlane32_swap repack,
// in-register row-sum l). K/V double-buffered with register prefetch -> one
// barrier per 64-k tile. setprio(1) around MFMA clusters. outproj: bijective
// XCD swizzle grouped by r-block. conv/proj unchanged (attribution next round).

#define NB 2
#define LSEQ 2048
#define EMB 1024
#define NHEADS 16
#define HD 64

// (1/sqrt(1024)) * log2(e): folded into Wq bf16 conversion; P = exp2(S+bias)
#define QSCALE 0.045084220027780106f
#define MASKBIAS -1e30f

using short8 = __attribute__((ext_vector_type(8))) short;
using short4v = __attribute__((ext_vector_type(4))) short;
using f32x4 = __attribute__((ext_vector_type(4))) float;
using f32x16 = __attribute__((ext_vector_type(16))) float;
using uint2v = __attribute__((ext_vector_type(2))) unsigned int;

__device__ inline short bf16of(float f) {
  union { __hip_bfloat16 b; short s; } u;
  u.b = __float2bfloat16(f);
  return u.s;
}

__device__ inline short4v pack4bf(float a, float b, float c, float d) {
  union { __hip_bfloat162 v[2]; short4v s; } u;
  u.v[0] = __float22bfloat162_rn(make_float2(a, b));
  u.v[1] = __float22bfloat162_rn(make_float2(c, d));
  return u.s;
}

__device__ inline short8 pack8bf(float4 a, float4 b) {
  union { short4v q[2]; short8 o; } u;
  u.q[0] = pack4bf(a.x, a.y, a.z, a.w);
  u.q[1] = pack4bf(b.x, b.y, b.z, b.w);
  return u.o;
}

__device__ inline unsigned pk2(float lo, float hi) {
  union { __hip_bfloat162 v; unsigned u; } x;
  x.v = __float22bfloat162_rn(make_float2(lo, hi));
  return x.u;
}

// v_permlane32_swap_b32: a' = {a.lo, b.lo}, b' = {a.hi, b.hi}
__device__ inline void plswap(unsigned& a, unsigned& b) {
#if __has_builtin(__builtin_amdgcn_permlane32_swap)
  uint2v r = __builtin_amdgcn_permlane32_swap(a, b, false, false);
  a = r[0];
  b = r[1];
#else
  asm volatile("v_permlane32_swap_b32 %0, %1" : "+v"(a), "+v"(b));
#endif
}

__device__ inline float fexp2(float x) {
#if __has_builtin(__builtin_amdgcn_exp2f)
  return __builtin_amdgcn_exp2f(x);
#else
  return exp2f(x);
#endif
}

#define MFMA(A, B, C) __builtin_amdgcn_mfma_f32_16x16x32_bf16((A), (B), (C), 0, 0, 0)
#define MFMA32(A, B, C) __builtin_amdgcn_mfma_f32_32x32x16_bf16((A), (B), (C), 0, 0, 0)

// ---------------------------------------------------------------------------
// Convert Wo->bf16 (grid-wide), Wq(*QSCALE)/Wk/Wv->bf16 (blocks 0-2),
// mask->bias float (blocks 4-7).
__global__ __launch_bounds__(256) void conv_kernel(
    const float* __restrict__ Wq, const float* __restrict__ Wk,
    const float* __restrict__ Wv, const float* __restrict__ Wo,
    const int* __restrict__ mask, short* __restrict__ Wqb,
    short* __restrict__ Wkb, short* __restrict__ Wvb,
    short* __restrict__ Wob, float* __restrict__ biasf) {
  const int b = blockIdx.x, t = threadIdx.x;
  {
    int i = (b * 256 + t) * 4;  // 1024 blocks * 1024 = 1Mi elements of Wo
    float4 v = *(const float4*)&Wo[i];
    *(short4v*)&Wob[i] = pack4bf(v.x, v.y, v.z, v.w);
  }
  if (b < 3) {
    const float* src = (b == 0) ? Wq : (b == 1) ? Wk : Wv;
    short* dst = (b == 0) ? Wqb : (b == 1) ? Wkb : Wvb;
    const float sc = (b == 0) ? QSCALE : 1.0f;
#pragma unroll
    for (int i = 0; i < 4; ++i) {
      int j = t * 16 + i * 4;  // 256*16 = 4096
      float4 v = *(const float4*)&src[j];
      *(short4v*)&dst[j] = pack4bf(v.x * sc, v.y * sc, v.z * sc, v.w * sc);
    }
  } else if (b >= 4 && b < 8) {
    int i = ((b - 4) * 256 + t) * 4;  // 4096 mask ints
    int4 m = *(const int4*)&mask[i];
    float4 o;
    o.x = m.x ? 0.f : MASKBIAS;
    o.y = m.y ? 0.f : MASKBIAS;
    o.z = m.z ? 0.f : MASKBIAS;
    o.w = m.w ? 0.f : MASKBIAS;
    *(float4*)&biasf[i] = o;
  }
}

// ---------------------------------------------------------------------------
// LDS-free MFMA projections. Block = 4 waves, 64 l-rows, one (n,h,z).
// z<2 (Q,K): C = W * x^T (M=d, N=l) -> C cols = l (lane l15), rows = d ->
//   short4v stores into row-major [l][d].
// z==2 (V): C = x * W^T (M=l, N=d) -> C cols = d, rows = l -> short4v
//   stores into V^T [d][L].
__global__ __launch_bounds__(256) void proj_mfma(
    const float* __restrict__ xq, const float* __restrict__ xk,
    const float* __restrict__ xv, const short* __restrict__ Wqb,
    const short* __restrict__ Wkb, const short* __restrict__ Wvb,
    short* __restrict__ Qb, short* __restrict__ Kb, short* __restrict__ Vt) {
  const int t = threadIdx.x;
  const int wq = t >> 6, lane = t & 63;
  const int quad = lane >> 4, l15 = lane & 15;
  const int z = blockIdx.z, nh = blockIdx.y;
  const int n = nh >> 4, h = nh & 15;
  const int l0 = blockIdx.x * 64;
  const float* x = (z == 0) ? xq : (z == 1) ? xk : xv;
  const short* W = (z == 0) ? Wqb : (z == 1) ? Wkb : Wvb;
  const int lrow = l0 + wq * 16 + l15;  // this lane's l (n-index for z<2)

  // x fragment: 8 f32 -> bf16, k = e chunk c*32+quad*8
  short8 xf[2];
  const float* xr = x + ((size_t)n * LSEQ + lrow) * EMB + h * HD;
#pragma unroll
  for (int c = 0; c < 2; ++c) {
    float4 a = *(const float4*)(xr + c * 32 + quad * 8);
    float4 b = *(const float4*)(xr + c * 32 + quad * 8 + 4);
    xf[c] = pack8bf(a, b);
  }
  // W fragments: row (mt*16+l15) of W[d][e] (A for z<2; B=W^T for z==2)
  short8 wf[4][2];
#pragma unroll
  for (int mt = 0; mt < 4; ++mt)
#pragma unroll
    for (int c = 0; c < 2; ++c)
      wf[mt][c] = *(const short8*)(W + (mt * 16 + l15) * HD + c * 32 + quad * 8);

  f32x4 acc[4];
#pragma unroll
  for (int a = 0; a < 4; ++a) acc[a] = (f32x4){0.f, 0.f, 0.f, 0.f};

  if (z < 2) {
#pragma unroll
    for (int c = 0; c < 2; ++c)
#pragma unroll
      for (int mt = 0; mt < 4; ++mt) acc[mt] = MFMA(wf[mt][c], xf[c], acc[mt]);
    short* ob = ((z == 0) ? Qb : Kb) + ((size_t)nh * LSEQ + lrow) * HD;
#pragma unroll
    for (int mt = 0; mt < 4; ++mt)
      *(short4v*)&ob[mt * 16 + quad * 4] =
          pack4bf(acc[mt][0], acc[mt][1], acc[mt][2], acc[mt][3]);
  } else {
#pragma unroll
    for (int c = 0; c < 2; ++c)
#pragma unroll
      for (int nt = 0; nt < 4; ++nt) acc[nt] = MFMA(xf[c], wf[nt][c], acc[nt]);
    // C rows = l = l0 + wq*16 + quad*4 + r ; cols = d = nt*16+l15
#pragma unroll
    for (int nt = 0; nt < 4; ++nt)
      *(short4v*)&Vt[((size_t)nh * HD + nt * 16 + l15) * LSEQ + l0 + wq * 16 +
                     quad * 4] =
          pack4bf(acc[nt][0], acc[nt][1], acc[nt][2], acc[nt][3]);
  }
}

// ---------------------------------------------------------------------------
// Flash attention, 32x32 MFMA. Wave = 32 q; block = 4 waves = 128 q.
// Grid 512 (XCD-grouped: all 16 q-blocks of a head on one XCD -> K/V
// L2-resident). Double-buffered XOR-swizzled K/V LDS, register prefetch,
// ONE barrier per 64-k tile. Swapped QK^T (mfma(K,Q)): lane's St regs all
// belong to q = lane&31 -> in-register exp2 softmax + scalar row-sum l;
// P repacked to A-fragments with cvt_pk + permlane32_swap (no P LDS).
__global__ __launch_bounds__(256, 2) void attn_kernel(
    const short* __restrict__ Qg,    // [nh][L][64] bf16 (Wq pre-scaled)
    const short* __restrict__ Kg,    // [nh][L][64] bf16
    const short* __restrict__ Vtg,   // [nh][64][L] bf16
    const float* __restrict__ biasf, // [N][L]: 0 or -1e30
    short* __restrict__ AO)          // [N*L][E] bf16
{
  __shared__ __align__(16) short Ks[2][64 * 64];
  __shared__ __align__(16) short Vs[2][64 * 64];
  __shared__ float linv_s[4][32];

  const int t = threadIdx.x;
  const int wv = t >> 6, lane = t & 63;
  const int l31 = lane & 31, hi = lane >> 5;

  // XCD-grouped swizzle: 512 blocks, 64/XCD; nh = xcd*4 + (idx>>4).
  const int raw = blockIdx.x;
  const int xcd = raw & 7, idx = raw >> 3;
  const int nh = (xcd << 2) | (idx >> 4);
  const int q0 = (idx & 15) * 128;
  const int n = nh >> 4, h = nh & 15;

  const short* kbase = Kg + (size_t)nh * LSEQ * HD;
  const short* vbase = Vtg + (size_t)nh * HD * LSEQ;
  const float* bbase = biasf + n * LSEQ;

  // Q B-fragments: q = q0 + wv*32 + l31, d = s*16 + hi*8 + j
  short8 qf[4];
  {
    const short* qr =
        Qg + ((size_t)nh * LSEQ + q0 + wv * 32 + l31) * HD + hi * 8;
#pragma unroll
    for (int s = 0; s < 4; ++s) qf[s] = *(const short8*)(qr + s * 16);
  }

  // staging: 512 16B slots per array; thread t covers slots {t, t+256}
  const int r0s = t >> 3, cs = t & 7, r1s = r0s + 32;
  const int ld0 = r0s * 64 + ((cs ^ (r0s & 7)) * 8);
  const int ld1 = r1s * 64 + ((cs ^ (r1s & 7)) * 8);

  {  // prologue: stage tile 0 into buffer 0
    short8 k0 = *(const short8*)(kbase + (size_t)r0s * HD + cs * 8);
    short8 k1 = *(const short8*)(kbase + (size_t)r1s * HD + cs * 8);
    short8 v0 = *(const short8*)(vbase + (size_t)r0s * LSEQ + cs * 8);
    short8 v1 = *(const short8*)(vbase + (size_t)r1s * LSEQ + cs * 8);
    *(short8*)&Ks[0][ld0] = k0;
    *(short8*)&Ks[0][ld1] = k1;
    *(short8*)&Vs[0][ld0] = v0;
    *(short8*)&Vs[0][ld1] = v1;
  }
  __syncthreads();

  f32x16 O[2];
#pragma unroll
  for (int nt = 0; nt < 2; ++nt)
#pragma unroll
    for (int r = 0; r < 16; ++r) O[nt][r] = 0.f;
  float ls[4] = {0.f, 0.f, 0.f, 0.f};
  int cur = 0;

  for (int kt = 0; kt < LSEQ / 64; ++kt) {
    // bias-initialized S^T accumulators (k = kt*64 + g*32 + (r&3)+8*(r>>2)+4*hi)
    f32x16 St[2];
#pragma unroll
    for (int g = 0; g < 2; ++g) {
      const float* bb = bbase + kt * 64 + g * 32 + hi * 4;
#pragma unroll
      for (int rr = 0; rr < 4; ++rr) {
        f32x4 bv = *(const f32x4*)(bb + rr * 8);
        St[g][rr * 4 + 0] = bv[0];
        St[g][rr * 4 + 1] = bv[1];
        St[g][rr * 4 + 2] = bv[2];
        St[g][rr * 4 + 3] = bv[3];
      }
    }

    // prefetch next tile -> registers (consumed after PV)
    short8 kr0, kr1, vr0, vr1;
    if (kt < LSEQ / 64 - 1) {
      const short* kb = kbase + (size_t)(kt + 1) * 64 * HD;
      const short* vb = vbase + (kt + 1) * 64;
      kr0 = *(const short8*)(kb + (size_t)r0s * HD + cs * 8);
      kr1 = *(const short8*)(kb + (size_t)r1s * HD + cs * 8);
      vr0 = *(const short8*)(vb + (size_t)r0s * LSEQ + cs * 8);
      vr1 = *(const short8*)(vb + (size_t)r1s * LSEQ + cs * 8);
    }

    // ---- S^T = K*Q^T + bias (A = K rows, B = Q cols)
    const short* ksb = &Ks[cur][0];
    __builtin_amdgcn_s_setprio(1);
#pragma unroll
    for (int g = 0; g < 2; ++g) {
      const int row = g * 32 + l31;
      const int swb = row * 64;
#pragma unroll
      for (int s = 0; s < 4; ++s) {
        short8 kf =
            *(const short8*)(ksb + swb + (((s * 2 + hi) ^ (row & 7)) * 8));
        St[g] = MFMA32(kf, qf[s], St[g]);
      }
    }
    __builtin_amdgcn_s_setprio(0);

    // ---- P = exp2(St); in-register row-sum (all regs belong to q=l31)
#pragma unroll
    for (int g = 0; g < 2; ++g)
#pragma unroll
      for (int r = 0; r < 16; ++r) {
        float e = fexp2(St[g][r]);
        St[g][r] = e;
        ls[r & 3] += e;
      }

    // ---- repack St (C layout) -> A-fragments pa[s] (k = s*16 + hi*8 + j)
    short8 pa[4];
#pragma unroll
    for (int g = 0; g < 2; ++g) {
#pragma unroll
      for (int hf = 0; hf < 2; ++hf) {
        unsigned w0 = pk2(St[g][hf * 8 + 0], St[g][hf * 8 + 1]);
        unsigned w2 = pk2(St[g][hf * 8 + 4], St[g][hf * 8 + 5]);
        plswap(w0, w2);
        unsigned w1 = pk2(St[g][hf * 8 + 2], St[g][hf * 8 + 3]);
        unsigned w3 = pk2(St[g][hf * 8 + 6], St[g][hf * 8 + 7]);
        plswap(w1, w3);
        union { unsigned u[4]; short8 s; } uo;
        uo.u[0] = w0;
        uo.u[1] = w1;
        uo.u[2] = w2;
        uo.u[3] = w3;
        pa[g * 2 + hf] = uo.s;
      }
    }

    // ---- PV (A = P, B = V^T rows = d)
    const short* vsb = &Vs[cur][0];
    __builtin_amdgcn_s_setprio(1);
#pragma unroll
    for (int s = 0; s < 4; ++s) {
#pragma unroll
      for (int nt = 0; nt < 2; ++nt) {
        const int row = nt * 32 + l31;
        short8 vf =
            *(const short8*)(vsb + row * 64 + (((s * 2 + hi) ^ (row & 7)) * 8));
        O[nt] = MFMA32(pa[s], vf, O[nt]);
      }
    }
    __builtin_amdgcn_s_setprio(0);

    // ---- write next tile into the other buffer; one barrier per tile
    if (kt < LSEQ / 64 - 1) {
      short* kd = &Ks[cur ^ 1][0];
      short* vd = &Vs[cur ^ 1][0];
      *(short8*)&kd[ld0] = kr0;
      *(short8*)&kd[ld1] = kr1;
      *(short8*)&vd[ld0] = vr0;
      *(short8*)&vd[ld1] = vr1;
    }
    __syncthreads();
    cur ^= 1;
  }

  // ---- epilogue: l across the two lane-halves, broadcast 1/l via LDS
  float lsum = (ls[0] + ls[1]) + (ls[2] + ls[3]);
  float ltot = lsum + __shfl_xor(lsum, 32);
  if (hi == 0) linv_s[wv][l31] = 1.f / ltot;
  short* ob = AO + ((size_t)n * LSEQ + q0 + wv * 32) * EMB + h * HD;
#pragma unroll
  for (int r = 0; r < 16; ++r) {
    const int qr = (r & 3) + 8 * (r >> 2) + 4 * hi;
    const float li = linv_s[wv][qr];
    ob[(size_t)qr * EMB + l31] = bf16of(O[0][r] * li);
    ob[(size_t)qr * EMB + 32 + l31] = bf16of(O[1][r] * li);
  }
}

// ---------------------------------------------------------------------------
// Out-projection: C[r][j] = sum_e A[r][e]*Wo[j][e] + bo[j].
// 128x64 tile/block, grid 512, XCD-grouped by r-block (A-panel + W fit in
// one XCD's L2). XOR-swizzled LDS, double-buffered, register prefetch.
__global__ __launch_bounds__(256, 2) void outproj_mfma(
    const short* __restrict__ A, const short* __restrict__ W,
    const float* __restrict__ bo, float* __restrict__ C) {
  __shared__ __align__(16) short As[2][128 * 64];
  __shared__ __align__(16) short Bs[2][64 * 64];
  const int t = threadIdx.x;
  const int wq = t >> 6, lane = t & 63;
  const int quad = lane >> 4, l15 = lane & 15;
  // XCD-grouped: 512 blocks, 64/XCD; ry = xcd*4 + (idx>>4), jx = idx&15.
  const int raw = blockIdx.x;
  const int xcd = raw & 7, idx = raw >> 3;
  const int ry = (xcd << 2) | (idx >> 4);
  const int j0 = (idx & 15) * 64, r0 = ry * 128;

  f32x4 acc[2][4];
#pragma unroll
  for (int a = 0; a < 2; ++a)
#pragma unroll
    for (int b = 0; b < 4; ++b) acc[a][b] = (f32x4){0.f, 0.f, 0.f, 0.f};

  // A: 1024 slots (row = slot>>3, ch = slot&7); B: 512 slots.
  short8 ar[4], br[2];
#pragma unroll
  for (int i = 0; i < 4; ++i) {
    int slot = i * 256 + t, row = slot >> 3, ch = slot & 7;
    ar[i] = *(const short8*)(A + (size_t)(r0 + row) * EMB + ch * 8);
  }
#pragma unroll
  for (int i = 0; i < 2; ++i) {
    int slot = i * 256 + t, row = slot >> 3, ch = slot & 7;
    br[i] = *(const short8*)(W + (size_t)(j0 + row) * EMB + ch * 8);
  }
#pragma unroll
  for (int i = 0; i < 4; ++i) {
    int slot = i * 256 + t, row = slot >> 3, ch = slot & 7;
    *(short8*)&As[0][row * 64 + ((ch ^ (row & 7)) * 8)] = ar[i];
  }
#pragma unroll
  for (int i = 0; i < 2; ++i) {
    int slot = i * 256 + t, row = slot >> 3, ch = slot & 7;
    *(short8*)&Bs[0][row * 64 + ((ch ^ (row & 7)) * 8)] = br[i];
  }
  __syncthreads();

  const int sw0 = ((0 * 4 + quad) ^ (l15 & 7)) * 8;
  const int sw1 = ((1 * 4 + quad) ^ (l15 & 7)) * 8;

  for (int ek = 0; ek < EMB; ek += 64) {
    const int cur = (ek >> 6) & 1, nxt = cur ^ 1;
    if (ek + 64 < EMB) {
#pragma unroll
      for (int i = 0; i < 4; ++i) {
        int slot = i * 256 + t, row = slot >> 3, ch = slot & 7;
        ar[i] = *(const short8*)(A + (size_t)(r0 + row) * EMB + ek + 64 + ch * 8);
      }
#pragma unroll
      for (int i = 0; i < 2; ++i) {
        int slot = i * 256 + t, row = slot >> 3, ch = slot & 7;
        br[i] = *(const short8*)(W + (size_t)(j0 + row) * EMB + ek + 64 + ch * 8);
      }
    }
#pragma unroll
    for (int c = 0; c < 2; ++c) {
      const int sw = c ? sw1 : sw0;
      short8 af[2], bf[4];
#pragma unroll
      for (int mt = 0; mt < 2; ++mt)
        af[mt] = *(const short8*)&As[cur][(wq * 32 + mt * 16 + l15) * 64 + sw];
#pragma unroll
      for (int nt = 0; nt < 4; ++nt)
        bf[nt] = *(const short8*)&Bs[cur][(nt * 16 + l15) * 64 + sw];
#pragma unroll
      for (int mt = 0; mt < 2; ++mt)
#pragma unroll
        for (int nt = 0; nt < 4; ++nt)
          acc[mt][nt] = MFMA(af[mt], bf[nt], acc[mt][nt]);
    }
    if (ek + 64 < EMB) {
#pragma unroll
      for (int i = 0; i < 4; ++i) {
        int slot = i * 256 + t, row = slot >> 3, ch = slot & 7;
        *(short8*)&As[nxt][row * 64 + ((ch ^ (row & 7)) * 8)] = ar[i];
      }
#pragma unroll
      for (int i = 0; i < 2; ++i) {
        int slot = i * 256 + t, row = slot >> 3, ch = slot & 7;
        *(short8*)&Bs[nxt][row * 64 + ((ch ^ (row & 7)) * 8)] = br[i];
      }
    }
    __syncthreads();
  }

  float bn[4];
#pragma unroll
  for (int nt = 0; nt < 4; ++nt) bn[nt] = bo[j0 + nt * 16 + l15];
#pragma unroll
  for (int mt = 0; mt < 2; ++mt)
#pragma unroll
    for (int nt = 0; nt < 4; ++nt)
#pragma unroll
      for (int r = 0; r < 4; ++r)
        C[(size_t)(r0 + wq * 32 + mt * 16 + quad * 4 + r) * EMB + j0 +
          nt * 16 + l15] = acc[mt][nt][r] + bn[nt];
}

// ---------------------------------------------------------------------------
extern "C" void kernel_launch(void* const* d_in, const int* in_sizes, int n_in,
                              void* d_out, int out_size, void* d_ws,
                              size_t ws_size, hipStream_t stream) {
  const float* values = (const float*)d_in[0];
  const float* keys   = (const float*)d_in[1];
  const float* query  = (const float*)d_in[2];
  const int*   mask   = (const int*)d_in[3];
  const float* Wv     = (const float*)d_in[4];
  const float* Wk     = (const float*)d_in[5];
  const float* Wq     = (const float*)d_in[6];
  const float* Wo     = (const float*)d_in[7];
  const float* bo     = (const float*)d_in[8];
  float* out = (float*)d_out;

  short* ws = (short*)d_ws;
  const size_t tsz = (size_t)NB * NHEADS * LSEQ * HD;  // 4 Mi shorts
  short* Qb  = ws;
  short* Kb  = Qb + tsz;
  short* Vt  = Kb + tsz;
  short* AOb = Vt + tsz;
  short* Wob = AOb + tsz;               // 1 Mi shorts
  float* biasf = (float*)(Wob + (size_t)EMB * EMB);  // 4096 floats
  short* Wqb = (short*)(biasf + NB * LSEQ);
  short* Wkb = Wqb + HD * HD;
  short* Wvb = Wkb + HD * HD;

  dim3 blk(256);
  conv_kernel<<<dim3(1024), blk, 0, stream>>>(Wq, Wk, Wv, Wo, mask, Wqb, Wkb,
                                              Wvb, Wob, biasf);
  proj_mfma<<<dim3(LSEQ / 64, NB * NHEADS, 3), blk, 0, stream>>>(
      query, keys, values, Wqb, Wkb, Wvb, Qb, Kb, Vt);
  attn_kernel<<<dim3(512), blk, 0, stream>>>(Qb, Kb, Vt, biasf, AOb);
  outproj_mfma<<<dim3(512), blk, 0, stream>>>(AOb, Wob, bo, out);
}